// Round 4
// baseline (48.666 us; speedup 1.0000x reference)
//
#include <hip/hip_runtime.h>

// Output: K (8192, 8192) f32 = 256 MB. Pure write-stream bound.
// 2D launch: blockIdx.y = i (row pair), x covers jp (j-pairs).
// Each thread handles TWO j-pairs (jp and jp+blockDim) -> 4 nontemporal
// 16B stores, each instruction fully coalesced (lanes at 16B stride).

typedef float v4f __attribute__((ext_vector_type(4)));

__device__ __forceinline__ void compute_pair(float xi0, float xi1, v4f y,
                                             float inv_ls, v4f& r0, v4f& r1) {
    {   // first j (y[0], y[1])
        const float dx = xi0 - y[0];
        const float dy = xi1 - y[1];
        const float t  = (dx * dx + dy * dy) * inv_ls;   // dist/ls
        const float ke = __expf(-0.5f * t);              // SIGMA_VAR = 1
        const float c  = 1.0f - t;                       // (d-1) - dist/ls
        r0[0] = (dx * dx * inv_ls + c) * ke;             // A00
        r0[1] = (dx * dy * inv_ls) * ke;                 // A01
        r1[0] = r0[1];                                   // A10
        r1[1] = (dy * dy * inv_ls + c) * ke;             // A11
    }
    {   // second j (y[2], y[3])
        const float dx = xi0 - y[2];
        const float dy = xi1 - y[3];
        const float t  = (dx * dx + dy * dy) * inv_ls;
        const float ke = __expf(-0.5f * t);
        const float c  = 1.0f - t;
        r0[2] = (dx * dx * inv_ls + c) * ke;
        r0[3] = (dx * dy * inv_ls) * ke;
        r1[2] = r0[3];
        r1[3] = (dy * dy * inv_ls + c) * ke;
    }
}

__global__ void __launch_bounds__(512) rbf_divfree_kernel(
    const float* __restrict__ X,        // (n, 2)
    const float* __restrict__ Y,        // (m, 2)
    const float* __restrict__ lls,      // (1,)
    float* __restrict__ out,            // (2n, 2m) row-major
    int mp)                             // mp = m/2 (j-pairs per row)
{
    const int tid  = threadIdx.x;
    const int i    = blockIdx.y;
    const int jpA  = blockIdx.x * (blockDim.x * 2) + tid;   // first j-pair
    const int jpB  = jpA + blockDim.x;                      // second j-pair

    const float inv_ls = __expf(-lls[0]);        // 1/ls
    const size_t ldc = (size_t)mp * 4;           // output row stride = 2m

    const float xi0 = X[2 * i];
    const float xi1 = X[2 * i + 1];
    const v4f yA = *reinterpret_cast<const v4f*>(Y + 4 * (size_t)jpA);
    const v4f yB = *reinterpret_cast<const v4f*>(Y + 4 * (size_t)jpB);

    v4f r0A, r1A, r0B, r1B;
    compute_pair(xi0, xi1, yA, inv_ls, r0A, r1A);
    compute_pair(xi0, xi1, yB, inv_ls, r0B, r1B);

    float* p0 = out + (size_t)(2 * i) * ldc + 4 * (size_t)jpA;
    const size_t db = 4 * (size_t)blockDim.x;    // 512*4 floats = 8 KB
    __builtin_nontemporal_store(r0A, reinterpret_cast<v4f*>(p0));
    __builtin_nontemporal_store(r0B, reinterpret_cast<v4f*>(p0 + db));
    __builtin_nontemporal_store(r1A, reinterpret_cast<v4f*>(p0 + ldc));
    __builtin_nontemporal_store(r1B, reinterpret_cast<v4f*>(p0 + ldc + db));
}

extern "C" void kernel_launch(void* const* d_in, const int* in_sizes, int n_in,
                              void* d_out, int out_size, void* d_ws, size_t ws_size,
                              hipStream_t stream) {
    const float* X   = (const float*)d_in[0];
    const float* Y   = (const float*)d_in[1];
    const float* lls = (const float*)d_in[2];
    float* out = (float*)d_out;

    const int n  = in_sizes[0] / 2;   // 4096
    const int m  = in_sizes[1] / 2;   // 4096
    const int mp = m / 2;             // 2048 j-pairs

    const int block = 512;
    dim3 grid(mp / (block * 2), n);   // (2, 4096) = 8192 blocks

    rbf_divfree_kernel<<<grid, block, 0, stream>>>(X, Y, lls, out, mp);
}

// Round 5
// 43.774 us; speedup vs baseline: 1.1117x; 1.1117x over previous
//
#include <hip/hip_runtime.h>

// Output: K (8192, 8192) f32 = 256 MB. Pure write-stream bound.
// Shape mimics __amd_rocclr_fillBufferAligned (7.0 TB/s on this chip):
// 256-thread blocks, each thread ONE plain float4 store, each block a
// contiguous 4 KB span. blockIdx.y = output row (8192), x covers float4 cols.
// Row parity d1 = row & 1 selects which 2x2-block row to emit (uniform).

typedef float v4f __attribute__((ext_vector_type(4)));

__global__ void __launch_bounds__(256) rbf_divfree_kernel(
    const float* __restrict__ X,        // (n, 2)
    const float* __restrict__ Y,        // (m, 2)
    const float* __restrict__ lls,      // (1,)
    float* __restrict__ out,            // (2n, 2m) row-major
    int mp)                             // mp = m/2 = float4 cols per row
{
    const int jp  = blockIdx.x * blockDim.x + threadIdx.x;  // float4 col
    const int row = blockIdx.y;                              // output row
    const int i   = row >> 1;
    const int d1  = row & 1;            // block-uniform

    const float inv_ls = __expf(-lls[0]);        // 1/ls
    const float xi0 = X[2 * i];
    const float xi1 = X[2 * i + 1];
    const v4f y = *reinterpret_cast<const v4f*>(Y + 4 * (size_t)jp);

    v4f r;
    {   // j = 2*jp  (y[0], y[1])
        const float dx = xi0 - y[0];
        const float dy = xi1 - y[1];
        const float t  = (dx * dx + dy * dy) * inv_ls;   // dist/ls
        const float ke = __expf(-0.5f * t);              // SIGMA_VAR = 1
        const float c  = 1.0f - t;                       // (d-1) - dist/ls
        const float a  = d1 ? dy : dx;                   // diff[d1]
        r[0] = (dx * a * inv_ls + (d1 ? 0.0f : c)) * ke; // A[d1][0]
        r[1] = (dy * a * inv_ls + (d1 ? c : 0.0f)) * ke; // A[d1][1]
    }
    {   // j = 2*jp+1  (y[2], y[3])
        const float dx = xi0 - y[2];
        const float dy = xi1 - y[3];
        const float t  = (dx * dx + dy * dy) * inv_ls;
        const float ke = __expf(-0.5f * t);
        const float c  = 1.0f - t;
        const float a  = d1 ? dy : dx;
        r[2] = (dx * a * inv_ls + (d1 ? 0.0f : c)) * ke;
        r[3] = (dy * a * inv_ls + (d1 ? c : 0.0f)) * ke;
    }

    float* p = out + (size_t)row * ((size_t)mp * 4) + 4 * (size_t)jp;
    *reinterpret_cast<v4f*>(p) = r;     // plain coalesced 16B store
}

extern "C" void kernel_launch(void* const* d_in, const int* in_sizes, int n_in,
                              void* d_out, int out_size, void* d_ws, size_t ws_size,
                              hipStream_t stream) {
    const float* X   = (const float*)d_in[0];
    const float* Y   = (const float*)d_in[1];
    const float* lls = (const float*)d_in[2];
    float* out = (float*)d_out;

    const int n  = in_sizes[0] / 2;   // 4096
    const int m  = in_sizes[1] / 2;   // 4096
    const int mp = m / 2;             // 2048 float4 columns

    const int block = 256;
    dim3 grid(mp / block, 2 * n);     // (8, 8192) = 65536 blocks

    rbf_divfree_kernel<<<grid, block, 0, stream>>>(X, Y, lls, out, mp);
}

// Round 6
// 43.250 us; speedup vs baseline: 1.1252x; 1.0121x over previous
//
#include <hip/hip_runtime.h>

// Output: K (8192, 8192) f32 = 256 MB. Pure write-stream bound.
// Same per-thread shape as R5 (one plain float4 store), but 1024-thread
// blocks -> 16384 workgroups (4x fewer) to relieve wg-dispatch pressure.
// blockIdx.y = output row (8192), x covers float4 cols (2 blocks/row).
// Row parity d1 = row & 1 selects which 2x2-block row to emit (uniform).

typedef float v4f __attribute__((ext_vector_type(4)));

__global__ void __launch_bounds__(1024) rbf_divfree_kernel(
    const float* __restrict__ X,        // (n, 2)
    const float* __restrict__ Y,        // (m, 2)
    const float* __restrict__ lls,      // (1,)
    float* __restrict__ out,            // (2n, 2m) row-major
    int mp)                             // mp = m/2 = float4 cols per row
{
    const int jp  = blockIdx.x * blockDim.x + threadIdx.x;  // float4 col
    const int row = blockIdx.y;                              // output row
    const int i   = row >> 1;
    const int d1  = row & 1;            // block-uniform

    const float inv_ls = __expf(-lls[0]);        // 1/ls
    const float xi0 = X[2 * i];
    const float xi1 = X[2 * i + 1];
    const v4f y = *reinterpret_cast<const v4f*>(Y + 4 * (size_t)jp);

    v4f r;
    {   // j = 2*jp  (y[0], y[1])
        const float dx = xi0 - y[0];
        const float dy = xi1 - y[1];
        const float t  = (dx * dx + dy * dy) * inv_ls;   // dist/ls
        const float ke = __expf(-0.5f * t);              // SIGMA_VAR = 1
        const float c  = 1.0f - t;                       // (d-1) - dist/ls
        const float a  = d1 ? dy : dx;                   // diff[d1]
        r[0] = (dx * a * inv_ls + (d1 ? 0.0f : c)) * ke; // A[d1][0]
        r[1] = (dy * a * inv_ls + (d1 ? c : 0.0f)) * ke; // A[d1][1]
    }
    {   // j = 2*jp+1  (y[2], y[3])
        const float dx = xi0 - y[2];
        const float dy = xi1 - y[3];
        const float t  = (dx * dx + dy * dy) * inv_ls;
        const float ke = __expf(-0.5f * t);
        const float c  = 1.0f - t;
        const float a  = d1 ? dy : dx;
        r[2] = (dx * a * inv_ls + (d1 ? 0.0f : c)) * ke;
        r[3] = (dy * a * inv_ls + (d1 ? c : 0.0f)) * ke;
    }

    float* p = out + (size_t)row * ((size_t)mp * 4) + 4 * (size_t)jp;
    *reinterpret_cast<v4f*>(p) = r;     // plain coalesced 16B store
}

extern "C" void kernel_launch(void* const* d_in, const int* in_sizes, int n_in,
                              void* d_out, int out_size, void* d_ws, size_t ws_size,
                              hipStream_t stream) {
    const float* X   = (const float*)d_in[0];
    const float* Y   = (const float*)d_in[1];
    const float* lls = (const float*)d_in[2];
    float* out = (float*)d_out;

    const int n  = in_sizes[0] / 2;   // 4096
    const int m  = in_sizes[1] / 2;   // 4096
    const int mp = m / 2;             // 2048 float4 columns

    const int block = 1024;
    dim3 grid(mp / block, 2 * n);     // (2, 8192) = 16384 blocks

    rbf_divfree_kernel<<<grid, block, 0, stream>>>(X, Y, lls, out, mp);
}